// Round 8
// baseline (547.335 us; speedup 1.0000x reference)
//
#include <hip/hip_runtime.h>

// Predictive-coding graph message passing, MI355X — round 18.
// MEASUREMENT ROUND. Six structural rewrites (R12-R17) all landed at
// 107-110us; every per-kernel cost has been inferred, never measured (all
// five kernels hide below the 41.5us fill cutoff in top-5). The one time a
// kernel became visible (R13 k_bucket) my cycle model was 5x optimistic.
// R18 = R14 (best, 107.5us) with every kernel body wrapped in an
// IDEMPOTENT x16 repeat loop: results bit-identical, durations inflate 16x
// so the slowest kernel surfaces in top-5 WITH its counters. Readout:
//   dur ~= structural + 16*K  ->  exact total kernel time K
//   top-5 kernel identity + VALUBusy/conflicts/occupancy -> why it's slow
// R19 reverts the loop and applies the indicated fix.

static constexpr int kB = 32, kLogB = 5;
static constexpr int kBkt = 256;        // coarse buckets (16 nodes each)
static constexpr int kNPB = 16;         // nodes per bucket
static constexpr int kChunk = 2048;     // edges per chunk block
static constexpr int kTile = 2560;      // pass LDS tile (mean 2048, +11sigma)
static constexpr int kReps = 16;        // measurement inflation factor

// ---- K1: per-chunk dual histograms + fused transpose/tanh. --------------
__global__ void __launch_bounds__(1024) k_hist(
    const int* __restrict__ esrc, const int* __restrict__ edst,
    const float* __restrict__ x, float* __restrict__ x_t,
    float* __restrict__ fx_t, unsigned* __restrict__ cntA,
    unsigned* __restrict__ cntB, int N, int E, int nBB, int reps) {
  __shared__ unsigned hA[kBkt], hB[kBkt];
  __shared__ float tile[32][65];
  int tid = threadIdx.x, blk = blockIdx.x;
  for (int rep = 0; rep < reps; ++rep) {
    if (blk < nBB) {
      if (tid < kBkt) { hA[tid] = 0u; hB[tid] = 0u; }
      __syncthreads();
      int e0 = blk * kChunk, len = min(kChunk, E - e0);
      for (int i = tid; i < len; i += 1024) {
        atomicAdd(&hA[((unsigned)edst[e0 + i]) >> 4], 1u);  // ~8/bin: cheap
        atomicAdd(&hB[((unsigned)esrc[e0 + i]) >> 4], 1u);
      }
      __syncthreads();
      if (tid < kBkt) {                  // non-atomic coalesced row write
        cntA[(size_t)blk * kBkt + tid] = hA[tid];
        cntB[(size_t)blk * kBkt + tid] = hB[tid];
      }
    } else if (blk - nBB < (N >> 6)) {
      int n0 = (blk - nBB) * 64;
      for (int k = tid; k < 32 * 64; k += 1024) {  // coalesced 256B rows
        int b = k >> 6, n = k & 63;
        tile[b][n] = x[b * N + n0 + n];
      }
      __syncthreads();
      for (int k = tid; k < 64 * 32; k += 1024) {  // coalesced t-layout
        int n = k >> 5, b = k & 31;
        float xv = tile[b][n];
        int j = (n0 + n) * kB + b;
        x_t[j] = xv;
        fx_t[j] = tanhf(xv);
      }
    }
    __syncthreads();                     // rep boundary: LDS reuse
  }
}

// ---- K2: scan [chunk][bucket] counts -> absolute bases + segment bounds.
__global__ void __launch_bounds__(1024) k_scan(
    const unsigned* __restrict__ cntA, const unsigned* __restrict__ cntB,
    unsigned* __restrict__ baseA, unsigned* __restrict__ baseB,
    unsigned* __restrict__ segA, unsigned* __restrict__ segB, int nBB,
    int reps) {
  __shared__ unsigned qoff[4][kBkt];
  __shared__ unsigned tot[kBkt];
  __shared__ unsigned bb[kBkt];
  const unsigned* cnt = blockIdx.x ? cntB : cntA;
  unsigned* base = blockIdx.x ? baseB : baseA;
  unsigned* seg  = blockIdx.x ? segB  : segA;
  int tid = threadIdx.x;
  int t = tid & (kBkt - 1), q = tid >> 8;
  int qlen = (nBB + 3) >> 2;
  int b0 = q * qlen;
  for (int rep = 0; rep < reps; ++rep) {
    unsigned run = 0;
    for (int j = 0; j < qlen; j += 8) {
      unsigned c[8];
#pragma unroll
      for (int u = 0; u < 8; ++u) {      // 8 loads in flight
        int bi = b0 + j + u;
        c[u] = (bi < nBB) ? cnt[(size_t)bi * kBkt + t] : 0u;
      }
#pragma unroll
      for (int u = 0; u < 8; ++u) run += c[u];
    }
    qoff[q][t] = run;
    __syncthreads();
    unsigned myTot = 0;
    if (tid < kBkt) {                    // quarter offsets + bucket totals
      unsigned p0 = qoff[0][tid], p1 = qoff[1][tid];
      unsigned p2 = qoff[2][tid], p3 = qoff[3][tid];
      qoff[0][tid] = 0u; qoff[1][tid] = p0;
      qoff[2][tid] = p0 + p1; qoff[3][tid] = p0 + p1 + p2;
      myTot = p0 + p1 + p2 + p3;
      tot[tid] = myTot;
    }
    __syncthreads();
    for (int o = 1; o < kBkt; o <<= 1) { // Hillis-Steele over 256 totals
      unsigned v = 0;
      if (tid < kBkt && tid >= o) v = tot[tid - o];
      __syncthreads();
      if (tid < kBkt && tid >= o) tot[tid] += v;
      __syncthreads();
    }
    if (tid < kBkt) {
      unsigned excl = tot[tid] - myTot;
      bb[tid] = excl;
      seg[tid] = excl;                   // dense segment starts
      if (tid == kBkt - 1) seg[kBkt] = excl + myTot;
    }
    __syncthreads();
    unsigned run2 = bb[t] + qoff[q][t];  // replay: absolute bases
    for (int j = 0; j < qlen; j += 8) {
      unsigned c[8];
#pragma unroll
      for (int u = 0; u < 8; ++u) {
        int bi = b0 + j + u;
        c[u] = (bi < nBB) ? cnt[(size_t)bi * kBkt + t] : 0u;
      }
#pragma unroll
      for (int u = 0; u < 8; ++u) {
        int bi = b0 + j + u;
        if (bi < nBB) base[(size_t)bi * kBkt + t] = run2;
        run2 += c[u];
      }
    }
    __syncthreads();                     // rep boundary: LDS reuse
  }
}

// ---- K3: deterministic scatter into dense bucket segments. --------------
__global__ void __launch_bounds__(1024) k_scatter(
    const int* __restrict__ esrc, const int* __restrict__ edst,
    const float* __restrict__ wgt,
    const unsigned* __restrict__ cntA, const unsigned* __restrict__ cntB,
    const unsigned* __restrict__ baseA, const unsigned* __restrict__ baseB,
    uint2* __restrict__ recA, uint2* __restrict__ recB, int E, int nBB,
    int reps) {
  __shared__ unsigned myBase[kBkt], cntL[kBkt], baseL[kBkt], cnt2[kBkt];
  __shared__ uint2 cmp[kChunk];          // 16 KB chunk-sorted records
  __shared__ unsigned char bktid[kChunk];
  int tid = threadIdx.x, blk = blockIdx.x;
  int e0 = blk * kChunk, len = min(kChunk, E - e0);
  for (int rep = 0; rep < reps; ++rep) {
    for (int dir = 0; dir < 2; ++dir) {
      const int* key = dir ? esrc : edst;  // A: by dst, B: by src
      const int* oth = dir ? edst : esrc;
      const unsigned* cnt = dir ? cntB : cntA;
      const unsigned* base = dir ? baseB : baseA;
      uint2* out = dir ? recB : recA;
      if (tid < kBkt) {
        myBase[tid] = base[(size_t)blk * kBkt + tid];
        cntL[tid] = cnt[(size_t)blk * kBkt + tid];
        cnt2[tid] = 0u;
      }
      __syncthreads();
      if (tid < 64) {                    // single-wave excl scan, 4 bins/lane
        int qq = tid << 2;
        unsigned c0 = cntL[qq], c1 = cntL[qq + 1];
        unsigned c2 = cntL[qq + 2], c3 = cntL[qq + 3];
        unsigned s = c0 + c1 + c2 + c3, run = s;
#pragma unroll
        for (int o = 1; o < 64; o <<= 1) {
          unsigned v = __shfl_up(run, o, 64);
          if (tid >= o) run += v;
        }
        unsigned bse = run - s;
        baseL[qq] = bse; baseL[qq + 1] = bse + c0;
        baseL[qq + 2] = bse + c0 + c1; baseL[qq + 3] = bse + c0 + c1 + c2;
      }
      __syncthreads();
      for (int i = tid; i < len; i += 1024) {      // LDS sort
        unsigned ky = (unsigned)key[e0 + i], ot = (unsigned)oth[e0 + i];
        unsigned bbk = ky >> 4;
        unsigned slot = baseL[bbk] + atomicAdd(&cnt2[bbk], 1u);
        cmp[slot] = make_uint2((ot << 4) | (ky & 15u),
                               __float_as_uint(wgt[e0 + i]));
        bktid[slot] = (unsigned char)bbk;
      }
      __syncthreads();
      for (int s = tid; s < len; s += 1024) {      // coalesced run copy-out
        unsigned bbk = bktid[s];
        out[myBase[bbk] + ((unsigned)s - baseL[bbk])] = cmp[s];
      }
      __syncthreads();
    }
  }
}

// ---- K4/K5: per-bucket fine sort + select-free pipelined accumulation. --
__global__ void __launch_bounds__(1024) k_pass(
    const uint2* __restrict__ rec, const unsigned* __restrict__ seg,
    const float* __restrict__ vals, const float* __restrict__ x_t,
    const float* __restrict__ fx_t, float* __restrict__ eps_t,
    float* __restrict__ out, int N, int mode, int reps) {
  __shared__ uint2 stg[kTile];           // 20 KB staged records
  __shared__ uint2 srt[kTile];           // 20 KB node-sorted records
  __shared__ unsigned hW[16 * kNPB];     // per-wave private hist
  __shared__ unsigned wbase[16 * kNPB];  // absolute slot base per (wave,node)
  __shared__ unsigned wcur[16 * kNPB];
  __shared__ unsigned h[kNPB], hb[kNPB];
  __shared__ float red[1024];
  int tid = threadIdx.x, t = blockIdx.x;
  int segb = (int)seg[t], sege = (int)seg[t + 1];
  int wv = tid >> 6;
  int b = tid & 31, hw = tid >> 5, l = hw >> 1, part = hw & 1;

  for (int rep = 0; rep < reps; ++rep) {
    float acc = 0.0f;
    for (int t0 = segb; t0 < sege; t0 += kTile) {  // 1 tile except 11-sigma tail
      int len = min(kTile, sege - t0);
      if (tid < 16 * kNPB) { hW[tid] = 0u; wcur[tid] = 0u; }
      __syncthreads();
      for (int i = tid; i < len; i += 1024) {      // stage + privatized hist
        uint2 r = rec[t0 + i];
        stg[i] = r;
        atomicAdd(&hW[wv * kNPB + (r.x & 15u)], 1u);
      }
      __syncthreads();
      if (tid < kNPB) {                            // cross-wave prefix per node
        unsigned run = 0;
#pragma unroll
        for (int w2 = 0; w2 < 16; ++w2) {
          unsigned c = hW[w2 * kNPB + tid];
          wbase[w2 * kNPB + tid] = run;
          run += c;
        }
        h[tid] = run;
      }
      __syncthreads();
      if (tid == 0) {                              // 16-elem excl scan
        unsigned run = 0;
#pragma unroll
        for (int l2 = 0; l2 < kNPB; ++l2) { hb[l2] = run; run += h[l2]; }
      }
      __syncthreads();
      if (tid < 16 * kNPB) wbase[tid] += hb[tid & (kNPB - 1)];
      __syncthreads();
      for (int i = tid; i < len; i += 1024) {      // fine sort (LDS -> LDS)
        uint2 r = stg[i];
        unsigned lx = r.x & 15u;
        srt[wbase[wv * kNPB + lx] + atomicAdd(&wcur[wv * kNPB + lx], 1u)] = r;
      }
      __syncthreads();

      int beg = (int)hb[l] + part, end = (int)hb[l] + (int)h[l];
      int last = end - 1; if (last < 0) last = 0;
      uint2 r0, r1, r2, r3, r4, r5, r6, r7;
      float v0, v1, v2, v3, v4, v5, v6, v7;
#define PC_LOAD(d)                                                   \
      { int p = beg + 2 * (d); uint2 rr = srt[min(p, last)];         \
        r##d = rr; v##d = vals[(((rr.x >> 4) & 4095u) << kLogB) + b]; }
      PC_LOAD(0) PC_LOAD(1) PC_LOAD(2) PC_LOAD(3)
      PC_LOAD(4) PC_LOAD(5) PC_LOAD(6) PC_LOAD(7)
#undef PC_LOAD
      int i = beg;
      while (i < end) {
#define PC_STEP(d)                                                   \
        { float wt = (i + 2 * (d) < end) ? __uint_as_float(r##d.y) : 0.0f; \
          acc = fmaf(wt, v##d, acc);                                 \
          int p = i + 16 + 2 * (d); uint2 rr = srt[min(p, last)];    \
          r##d = rr; v##d = vals[(((rr.x >> 4) & 4095u) << kLogB) + b]; }
        PC_STEP(0) PC_STEP(1) PC_STEP(2) PC_STEP(3)
        PC_STEP(4) PC_STEP(5) PC_STEP(6) PC_STEP(7)
#undef PC_STEP
        i += 16;
      }
      __syncthreads();                             // srt/hW reused next tile
    }

    red[tid] = acc;
    __syncthreads();
    if (part == 0) {                               // combine 2 parts, write
      float s = red[tid] + red[tid + 32];
      int n = t * kNPB + l;
      int j = (n << kLogB) + b;
      if (mode == 0) {
        out[b * N + n] = s;                        // mu: full 64B line
        eps_t[j] = x_t[j] - s;
      } else {
        float fx = fx_t[j];
        out[b * N + n] = fmaf(1.0f - fx * fx, s, -eps_t[j]);  // dx
      }
    }
    __syncthreads();                               // rep boundary: red reuse
  }
}

extern "C" void kernel_launch(void* const* d_in, const int* in_sizes, int n_in,
                              void* d_out, int out_size, void* d_ws, size_t ws_size,
                              hipStream_t stream) {
  const float* x    = (const float*)d_in[0];
  const float* w    = (const float*)d_in[1];
  const int*   esrc = (const int*)d_in[2];
  const int*   edst = (const int*)d_in[3];

  int BN = in_sizes[0];                  // 131072
  int E  = in_sizes[1];                  // 524288
  int N  = BN / kB;                      // 4096
  int nBB = (E + kChunk - 1) / kChunk;   // 256

  float* ws    = (float*)d_ws;
  float* x_t   = ws;                     // [BN]
  float* fx_t  = ws + (size_t)BN;        // [BN]
  float* eps_t = ws + 2 * (size_t)BN;    // [BN]
  unsigned* cntA = (unsigned*)(ws + 3 * (size_t)BN);    // [nBB*256] 256 KB
  unsigned* cntB = cntA + (size_t)nBB * kBkt;
  unsigned* baseA = cntB + (size_t)nBB * kBkt;          // [nBB*256]
  unsigned* baseB = baseA + (size_t)nBB * kBkt;
  unsigned* segA = baseB + (size_t)nBB * kBkt;          // [257] (512 pad)
  unsigned* segB = segA + 512;
  uint2* recA = (uint2*)(segB + 512);                   // [E] 4 MB dense
  uint2* recB = recA + (size_t)E;                       // [E] 4 MB dense

  float* out_mu = (float*)d_out;
  float* out_dx = (float*)d_out + BN;

  k_hist<<<nBB + (N >> 6), 1024, 0, stream>>>(esrc, edst, x, x_t, fx_t,
                                              cntA, cntB, N, E, nBB, kReps);
  k_scan<<<2, 1024, 0, stream>>>(cntA, cntB, baseA, baseB, segA, segB, nBB,
                                 kReps);
  k_scatter<<<nBB, 1024, 0, stream>>>(esrc, edst, w, cntA, cntB, baseA, baseB,
                                      recA, recB, E, nBB, kReps);
  // Pass 1: mu[n] = sum_{e: dst=n} w_e * fx[src_e]; eps = x - mu.
  k_pass<<<kBkt, 1024, 0, stream>>>(recA, segA, fx_t, x_t, fx_t,
                                    eps_t, out_mu, N, 0, kReps);
  // Pass 2: dx[n] = -eps[n] + f'(x_n) * sum_{e: src=n} w_e * eps[dst_e].
  k_pass<<<kBkt, 1024, 0, stream>>>(recB, segB, eps_t, x_t, fx_t,
                                    eps_t, out_dx, N, 1, kReps);
}

// Round 9
// 101.873 us; speedup vs baseline: 5.3727x; 5.3727x over previous
//
#include <hip/hip_runtime.h>

// Predictive-coding graph message passing, MI355X — round 19.
// R18 measurement round resolved the budget: kernels K ~= 29us total,
// structural S ~= 78us (fills + gaps). Dominant kernel: k_scan at 9.8us —
// a 2-block (0.36% occupancy, 0.48% VALUBusy) latency-bound scan of the
// 256x256 count matrix. The passes are only ~4-5us each (six rounds of
// pass-tuning had nothing left to win). R19 deletes the k_scan DISPATCH:
// k_scatter becomes self-scanning — each of 512 blocks (one (dir,chunk),
// 2/CU) reads the L2-resident cnt matrix in a coalesced preamble, computes
// per-bucket {prefix over chunks < c, total} in one pass, shfl-scans the
// totals for global bucket bases, and derives its own run bases. The c==0
// block of each dir writes seg[257] for k_pass. 5 dispatches -> 4.
// k_hist / k_pass byte-identical to the R18-measured bodies (reps removed).

static constexpr int kB = 32, kLogB = 5;
static constexpr int kBkt = 256;        // coarse buckets (16 nodes each)
static constexpr int kNPB = 16;         // nodes per bucket
static constexpr int kChunk = 2048;     // edges per chunk block
static constexpr int kTile = 2560;      // pass LDS tile (mean 2048, +11sigma)

// ---- K1: per-chunk dual histograms + fused transpose/tanh. --------------
__global__ void __launch_bounds__(1024) k_hist(
    const int* __restrict__ esrc, const int* __restrict__ edst,
    const float* __restrict__ x, float* __restrict__ x_t,
    float* __restrict__ fx_t, unsigned* __restrict__ cntA,
    unsigned* __restrict__ cntB, int N, int E, int nBB) {
  __shared__ unsigned hA[kBkt], hB[kBkt];
  __shared__ float tile[32][65];
  int tid = threadIdx.x, blk = blockIdx.x;
  if (blk < nBB) {
    if (tid < kBkt) { hA[tid] = 0u; hB[tid] = 0u; }
    __syncthreads();
    int e0 = blk * kChunk, len = min(kChunk, E - e0);
    for (int i = tid; i < len; i += 1024) {
      atomicAdd(&hA[((unsigned)edst[e0 + i]) >> 4], 1u);  // ~8/bin: cheap
      atomicAdd(&hB[((unsigned)esrc[e0 + i]) >> 4], 1u);
    }
    __syncthreads();
    if (tid < kBkt) {                    // non-atomic coalesced row write
      cntA[(size_t)blk * kBkt + tid] = hA[tid];
      cntB[(size_t)blk * kBkt + tid] = hB[tid];
    }
  } else if (blk - nBB < (N >> 6)) {
    int n0 = (blk - nBB) * 64;
    for (int k = tid; k < 32 * 64; k += 1024) {  // coalesced 256B rows
      int b = k >> 6, n = k & 63;
      tile[b][n] = x[b * N + n0 + n];
    }
    __syncthreads();
    for (int k = tid; k < 64 * 32; k += 1024) {  // coalesced t-layout
      int n = k >> 5, b = k & 31;
      float xv = tile[b][n];
      int j = (n0 + n) * kB + b;
      x_t[j] = xv;
      fx_t[j] = tanhf(xv);
    }
  }
}

// ---- K2: self-scanning deterministic scatter. 512 blocks, one
// (direction, chunk) each, 2 blocks/CU. Preamble: coalesced read of the
// full L2-resident [chunk][bucket] cnt matrix; thread (q,t) sums quarter q
// of bucket t's column, tracking rows < c separately -> per-bucket
// {prefix, total} in ONE pass. Single-wave shfl scan of totals gives
// global bucket bases. No scan kernel, no base matrix. ----------------
__global__ void __launch_bounds__(1024) k_scatter(
    const int* __restrict__ esrc, const int* __restrict__ edst,
    const float* __restrict__ wgt,
    const unsigned* __restrict__ cntA, const unsigned* __restrict__ cntB,
    uint2* __restrict__ recA, uint2* __restrict__ recB,
    unsigned* __restrict__ segA, unsigned* __restrict__ segB,
    int E, int nBB) {
  __shared__ unsigned qpre[4][kBkt], qtot[4][kBkt];
  __shared__ unsigned colPre[kBkt], colTot[kBkt], segL[kBkt];
  __shared__ unsigned myBase[kBkt], cntL[kBkt], baseL[kBkt], cnt2[kBkt];
  __shared__ uint2 cmp[kChunk];          // 16 KB chunk-sorted records
  __shared__ unsigned char bktid[kChunk];
  int tid = threadIdx.x, blk = blockIdx.x;
  int dir = (blk >= nBB);
  int c = blk - (dir ? nBB : 0);
  const unsigned* cnt = dir ? cntB : cntA;
  uint2* out = dir ? recB : recA;

  // Preamble: full-matrix column sums with prefix-below-c.
  int t = tid & (kBkt - 1), q = tid >> 8;
  int qlen = (nBB + 3) >> 2;
  int r0 = q * qlen;
  unsigned pre = 0, tot = 0;
  for (int j = 0; j < qlen; j += 8) {
    unsigned cc[8];
#pragma unroll
    for (int u = 0; u < 8; ++u) {        // 8 coalesced loads in flight
      int row = r0 + j + u;
      cc[u] = (row < nBB) ? cnt[(size_t)row * kBkt + t] : 0u;
    }
#pragma unroll
    for (int u = 0; u < 8; ++u) {
      int row = r0 + j + u;
      tot += cc[u];
      if (row < c) pre += cc[u];         // exact prefix contribution
    }
  }
  qpre[q][t] = pre;
  qtot[q][t] = tot;
  __syncthreads();
  if (tid < kBkt) {
    colPre[tid] = qpre[0][tid] + qpre[1][tid] + qpre[2][tid] + qpre[3][tid];
    colTot[tid] = qtot[0][tid] + qtot[1][tid] + qtot[2][tid] + qtot[3][tid];
  }
  __syncthreads();
  if (tid < 64) {                        // single-wave excl scan of totals
    int qq = tid << 2;
    unsigned c0 = colTot[qq], c1 = colTot[qq + 1];
    unsigned c2 = colTot[qq + 2], c3 = colTot[qq + 3];
    unsigned s = c0 + c1 + c2 + c3, run = s;
#pragma unroll
    for (int o = 1; o < 64; o <<= 1) {
      unsigned v = __shfl_up(run, o, 64);
      if (tid >= o) run += v;
    }
    unsigned bse = run - s;
    segL[qq] = bse; segL[qq + 1] = bse + c0;
    segL[qq + 2] = bse + c0 + c1; segL[qq + 3] = bse + c0 + c1 + c2;
  }
  __syncthreads();
  if (c == 0 && tid < kBkt) {            // publish segment bounds for k_pass
    unsigned* seg = dir ? segB : segA;
    seg[tid] = segL[tid];
    if (tid == kBkt - 1) seg[kBkt] = segL[tid] + colTot[tid];
  }
  if (tid < kBkt) {
    myBase[tid] = segL[tid] + colPre[tid];   // this chunk's global run base
    cntL[tid] = cnt[(size_t)c * kBkt + tid];
    cnt2[tid] = 0u;
  }
  __syncthreads();
  if (tid < 64) {                        // local excl scan of this chunk
    int qq = tid << 2;
    unsigned c0 = cntL[qq], c1 = cntL[qq + 1];
    unsigned c2 = cntL[qq + 2], c3 = cntL[qq + 3];
    unsigned s = c0 + c1 + c2 + c3, run = s;
#pragma unroll
    for (int o = 1; o < 64; o <<= 1) {
      unsigned v = __shfl_up(run, o, 64);
      if (tid >= o) run += v;
    }
    unsigned bse = run - s;
    baseL[qq] = bse; baseL[qq + 1] = bse + c0;
    baseL[qq + 2] = bse + c0 + c1; baseL[qq + 3] = bse + c0 + c1 + c2;
  }
  __syncthreads();
  int e0 = c * kChunk, len = min(kChunk, E - e0);
  const int* key = dir ? esrc : edst;    // A: by dst, B: by src
  const int* oth = dir ? edst : esrc;
  for (int i = tid; i < len; i += 1024) {          // LDS sort
    unsigned ky = (unsigned)key[e0 + i], ot = (unsigned)oth[e0 + i];
    unsigned bbk = ky >> 4;
    unsigned slot = baseL[bbk] + atomicAdd(&cnt2[bbk], 1u);
    cmp[slot] = make_uint2((ot << 4) | (ky & 15u), __float_as_uint(wgt[e0 + i]));
    bktid[slot] = (unsigned char)bbk;
  }
  __syncthreads();
  for (int s = tid; s < len; s += 1024) {          // coalesced run copy-out
    unsigned bbk = bktid[s];
    out[myBase[bbk] + ((unsigned)s - baseL[bbk])] = cmp[s];
  }
}

// ---- K3/K4: per-bucket fine sort + select-free pipelined accumulation. --
// (R18-measured body, reps removed.) Records staged to LDS once; loads
// unconditional with clamped index; only the WEIGHT predicated.
__global__ void __launch_bounds__(1024) k_pass(
    const uint2* __restrict__ rec, const unsigned* __restrict__ seg,
    const float* __restrict__ vals, const float* __restrict__ x_t,
    const float* __restrict__ fx_t, float* __restrict__ eps_t,
    float* __restrict__ out, int N, int mode) {
  __shared__ uint2 stg[kTile];           // 20 KB staged records
  __shared__ uint2 srt[kTile];           // 20 KB node-sorted records
  __shared__ unsigned hW[16 * kNPB];     // per-wave private hist
  __shared__ unsigned wbase[16 * kNPB];  // absolute slot base per (wave,node)
  __shared__ unsigned wcur[16 * kNPB];
  __shared__ unsigned h[kNPB], hb[kNPB];
  __shared__ float red[1024];
  int tid = threadIdx.x, t = blockIdx.x;
  int segb = (int)seg[t], sege = (int)seg[t + 1];
  int wv = tid >> 6;
  int b = tid & 31, hw = tid >> 5, l = hw >> 1, part = hw & 1;
  float acc = 0.0f;

  for (int t0 = segb; t0 < sege; t0 += kTile) {    // 1 tile except 11-sigma tail
    int len = min(kTile, sege - t0);
    if (tid < 16 * kNPB) { hW[tid] = 0u; wcur[tid] = 0u; }
    __syncthreads();
    for (int i = tid; i < len; i += 1024) {        // stage + privatized hist
      uint2 r = rec[t0 + i];
      stg[i] = r;
      atomicAdd(&hW[wv * kNPB + (r.x & 15u)], 1u);
    }
    __syncthreads();
    if (tid < kNPB) {                              // cross-wave prefix per node
      unsigned run = 0;
#pragma unroll
      for (int w2 = 0; w2 < 16; ++w2) {
        unsigned c = hW[w2 * kNPB + tid];
        wbase[w2 * kNPB + tid] = run;
        run += c;
      }
      h[tid] = run;
    }
    __syncthreads();
    if (tid == 0) {                                // 16-elem excl scan
      unsigned run = 0;
#pragma unroll
      for (int l2 = 0; l2 < kNPB; ++l2) { hb[l2] = run; run += h[l2]; }
    }
    __syncthreads();
    if (tid < 16 * kNPB) wbase[tid] += hb[tid & (kNPB - 1)];
    __syncthreads();
    for (int i = tid; i < len; i += 1024) {        // fine sort (LDS -> LDS)
      uint2 r = stg[i];
      unsigned lx = r.x & 15u;
      srt[wbase[wv * kNPB + lx] + atomicAdd(&wcur[wv * kNPB + lx], 1u)] = r;
    }
    __syncthreads();

    int beg = (int)hb[l] + part, end = (int)hb[l] + (int)h[l];
    int last = end - 1; if (last < 0) last = 0;
    uint2 r0, r1, r2, r3, r4, r5, r6, r7;
    float v0, v1, v2, v3, v4, v5, v6, v7;
#define PC_LOAD(d)                                                   \
    { int p = beg + 2 * (d); uint2 rr = srt[min(p, last)];           \
      r##d = rr; v##d = vals[(((rr.x >> 4) & 4095u) << kLogB) + b]; }
    PC_LOAD(0) PC_LOAD(1) PC_LOAD(2) PC_LOAD(3)
    PC_LOAD(4) PC_LOAD(5) PC_LOAD(6) PC_LOAD(7)
#undef PC_LOAD
    int i = beg;
    while (i < end) {
#define PC_STEP(d)                                                   \
      { float wt = (i + 2 * (d) < end) ? __uint_as_float(r##d.y) : 0.0f; \
        acc = fmaf(wt, v##d, acc);                                   \
        int p = i + 16 + 2 * (d); uint2 rr = srt[min(p, last)];      \
        r##d = rr; v##d = vals[(((rr.x >> 4) & 4095u) << kLogB) + b]; }
      PC_STEP(0) PC_STEP(1) PC_STEP(2) PC_STEP(3)
      PC_STEP(4) PC_STEP(5) PC_STEP(6) PC_STEP(7)
#undef PC_STEP
      i += 16;
    }
    __syncthreads();                               // srt/hW reused next tile
  }

  red[tid] = acc;
  __syncthreads();
  if (part == 0) {                                 // combine 2 parts, write
    float s = red[tid] + red[tid + 32];
    int n = t * kNPB + l;
    int j = (n << kLogB) + b;
    if (mode == 0) {
      out[b * N + n] = s;                          // mu: full 64B line
      eps_t[j] = x_t[j] - s;
    } else {
      float fx = fx_t[j];
      out[b * N + n] = fmaf(1.0f - fx * fx, s, -eps_t[j]);  // dx
    }
  }
}

extern "C" void kernel_launch(void* const* d_in, const int* in_sizes, int n_in,
                              void* d_out, int out_size, void* d_ws, size_t ws_size,
                              hipStream_t stream) {
  const float* x    = (const float*)d_in[0];
  const float* w    = (const float*)d_in[1];
  const int*   esrc = (const int*)d_in[2];
  const int*   edst = (const int*)d_in[3];

  int BN = in_sizes[0];                  // 131072
  int E  = in_sizes[1];                  // 524288
  int N  = BN / kB;                      // 4096
  int nBB = (E + kChunk - 1) / kChunk;   // 256

  float* ws    = (float*)d_ws;
  float* x_t   = ws;                     // [BN]
  float* fx_t  = ws + (size_t)BN;        // [BN]
  float* eps_t = ws + 2 * (size_t)BN;    // [BN]
  unsigned* cntA = (unsigned*)(ws + 3 * (size_t)BN);    // [nBB*256] 256 KB
  unsigned* cntB = cntA + (size_t)nBB * kBkt;
  unsigned* segA = cntB + (size_t)nBB * kBkt;           // [257] (512 pad)
  unsigned* segB = segA + 512;
  uint2* recA = (uint2*)(segB + 512);                   // [E] 4 MB dense
  uint2* recB = recA + (size_t)E;                       // [E] 4 MB dense

  float* out_mu = (float*)d_out;
  float* out_dx = (float*)d_out + BN;

  k_hist<<<nBB + (N >> 6), 1024, 0, stream>>>(esrc, edst, x, x_t, fx_t,
                                              cntA, cntB, N, E, nBB);
  k_scatter<<<2 * nBB, 1024, 0, stream>>>(esrc, edst, w, cntA, cntB,
                                          recA, recB, segA, segB, E, nBB);
  // Pass 1: mu[n] = sum_{e: dst=n} w_e * fx[src_e]; eps = x - mu.
  k_pass<<<kBkt, 1024, 0, stream>>>(recA, segA, fx_t, x_t, fx_t,
                                    eps_t, out_mu, N, 0);
  // Pass 2: dx[n] = -eps[n] + f'(x_n) * sum_{e: src=n} w_e * eps[dst_e].
  k_pass<<<kBkt, 1024, 0, stream>>>(recB, segB, eps_t, x_t, fx_t,
                                    eps_t, out_dx, N, 1);
}

// Round 10
// 100.335 us; speedup vs baseline: 5.4551x; 1.0153x over previous
//
#include <hip/hip_runtime.h>

// Predictive-coding graph message passing, MI355X — round 20.
// R19 (101.9us, best): self-scanning scatter deleted the k_scan dispatch,
// but each of 512 scatter blocks re-read the full 256KB cnt matrix ->
// 512KB of L2 preamble traffic PER CU (~3.8us) — the dominant scatter cost.
// R20, one isolated change: kChunk 2048 -> 4096.
//   cnt matrix [256][256] -> [128][256]; scatter 512 -> 256 blocks (1/CU);
//   per-CU preamble traffic 512KB -> 128KB (-75%), aggregate 128MB -> 32MB;
//   copy-out runs 64B -> 128B mean. Edge/sort/pass work unchanged;
//   k_pass byte-identical to R19. Budget: S~74 structural + hist 4 +
//   scatter 8->5 + 2x pass 4.5. Predicted 97-99us.

static constexpr int kB = 32, kLogB = 5;
static constexpr int kBkt = 256;        // coarse buckets (16 nodes each)
static constexpr int kNPB = 16;         // nodes per bucket
static constexpr int kChunk = 4096;     // edges per chunk block (was 2048)
static constexpr int kTile = 2560;      // pass LDS tile (mean 2048, +11sigma)

// ---- K1: per-chunk dual histograms + fused transpose/tanh. --------------
__global__ void __launch_bounds__(1024) k_hist(
    const int* __restrict__ esrc, const int* __restrict__ edst,
    const float* __restrict__ x, float* __restrict__ x_t,
    float* __restrict__ fx_t, unsigned* __restrict__ cntA,
    unsigned* __restrict__ cntB, int N, int E, int nBB) {
  __shared__ unsigned hA[kBkt], hB[kBkt];
  __shared__ float tile[32][65];
  int tid = threadIdx.x, blk = blockIdx.x;
  if (blk < nBB) {
    if (tid < kBkt) { hA[tid] = 0u; hB[tid] = 0u; }
    __syncthreads();
    int e0 = blk * kChunk, len = min(kChunk, E - e0);
    for (int i = tid; i < len; i += 1024) {
      atomicAdd(&hA[((unsigned)edst[e0 + i]) >> 4], 1u);  // ~16/bin: cheap
      atomicAdd(&hB[((unsigned)esrc[e0 + i]) >> 4], 1u);
    }
    __syncthreads();
    if (tid < kBkt) {                    // non-atomic coalesced row write
      cntA[(size_t)blk * kBkt + tid] = hA[tid];
      cntB[(size_t)blk * kBkt + tid] = hB[tid];
    }
  } else if (blk - nBB < (N >> 6)) {
    int n0 = (blk - nBB) * 64;
    for (int k = tid; k < 32 * 64; k += 1024) {  // coalesced 256B rows
      int b = k >> 6, n = k & 63;
      tile[b][n] = x[b * N + n0 + n];
    }
    __syncthreads();
    for (int k = tid; k < 64 * 32; k += 1024) {  // coalesced t-layout
      int n = k >> 5, b = k & 31;
      float xv = tile[b][n];
      int j = (n0 + n) * kB + b;
      x_t[j] = xv;
      fx_t[j] = tanhf(xv);
    }
  }
}

// ---- K2: self-scanning deterministic scatter. 256 blocks (1/CU), one
// (direction, chunk) each. Preamble: coalesced read of the L2-resident
// [128][256] cnt matrix; thread (q,t) sums quarter q of bucket t's column,
// tracking rows < c separately -> per-bucket {prefix, total} in ONE pass.
// Single-wave shfl scan of totals gives global bucket bases. ------------
__global__ void __launch_bounds__(1024) k_scatter(
    const int* __restrict__ esrc, const int* __restrict__ edst,
    const float* __restrict__ wgt,
    const unsigned* __restrict__ cntA, const unsigned* __restrict__ cntB,
    uint2* __restrict__ recA, uint2* __restrict__ recB,
    unsigned* __restrict__ segA, unsigned* __restrict__ segB,
    int E, int nBB) {
  __shared__ unsigned qpre[4][kBkt], qtot[4][kBkt];
  __shared__ unsigned colPre[kBkt], colTot[kBkt], segL[kBkt];
  __shared__ unsigned myBase[kBkt], cntL[kBkt], baseL[kBkt], cnt2[kBkt];
  __shared__ uint2 cmp[kChunk];          // 32 KB chunk-sorted records
  __shared__ unsigned char bktid[kChunk];
  int tid = threadIdx.x, blk = blockIdx.x;
  int dir = (blk >= nBB);
  int c = blk - (dir ? nBB : 0);
  const unsigned* cnt = dir ? cntB : cntA;
  uint2* out = dir ? recB : recA;

  // Preamble: full-matrix column sums with prefix-below-c.
  int t = tid & (kBkt - 1), q = tid >> 8;
  int qlen = (nBB + 3) >> 2;
  int r0 = q * qlen;
  unsigned pre = 0, tot = 0;
  for (int j = 0; j < qlen; j += 8) {
    unsigned cc[8];
#pragma unroll
    for (int u = 0; u < 8; ++u) {        // 8 coalesced loads in flight
      int row = r0 + j + u;
      cc[u] = (row < nBB) ? cnt[(size_t)row * kBkt + t] : 0u;
    }
#pragma unroll
    for (int u = 0; u < 8; ++u) {
      int row = r0 + j + u;
      tot += cc[u];
      if (row < c) pre += cc[u];         // exact prefix contribution
    }
  }
  qpre[q][t] = pre;
  qtot[q][t] = tot;
  __syncthreads();
  if (tid < kBkt) {
    colPre[tid] = qpre[0][tid] + qpre[1][tid] + qpre[2][tid] + qpre[3][tid];
    colTot[tid] = qtot[0][tid] + qtot[1][tid] + qtot[2][tid] + qtot[3][tid];
  }
  __syncthreads();
  if (tid < 64) {                        // single-wave excl scan of totals
    int qq = tid << 2;
    unsigned c0 = colTot[qq], c1 = colTot[qq + 1];
    unsigned c2 = colTot[qq + 2], c3 = colTot[qq + 3];
    unsigned s = c0 + c1 + c2 + c3, run = s;
#pragma unroll
    for (int o = 1; o < 64; o <<= 1) {
      unsigned v = __shfl_up(run, o, 64);
      if (tid >= o) run += v;
    }
    unsigned bse = run - s;
    segL[qq] = bse; segL[qq + 1] = bse + c0;
    segL[qq + 2] = bse + c0 + c1; segL[qq + 3] = bse + c0 + c1 + c2;
  }
  __syncthreads();
  if (c == 0 && tid < kBkt) {            // publish segment bounds for k_pass
    unsigned* seg = dir ? segB : segA;
    seg[tid] = segL[tid];
    if (tid == kBkt - 1) seg[kBkt] = segL[tid] + colTot[tid];
  }
  if (tid < kBkt) {
    myBase[tid] = segL[tid] + colPre[tid];   // this chunk's global run base
    cntL[tid] = cnt[(size_t)c * kBkt + tid];
    cnt2[tid] = 0u;
  }
  __syncthreads();
  if (tid < 64) {                        // local excl scan of this chunk
    int qq = tid << 2;
    unsigned c0 = cntL[qq], c1 = cntL[qq + 1];
    unsigned c2 = cntL[qq + 2], c3 = cntL[qq + 3];
    unsigned s = c0 + c1 + c2 + c3, run = s;
#pragma unroll
    for (int o = 1; o < 64; o <<= 1) {
      unsigned v = __shfl_up(run, o, 64);
      if (tid >= o) run += v;
    }
    unsigned bse = run - s;
    baseL[qq] = bse; baseL[qq + 1] = bse + c0;
    baseL[qq + 2] = bse + c0 + c1; baseL[qq + 3] = bse + c0 + c1 + c2;
  }
  __syncthreads();
  int e0 = c * kChunk, len = min(kChunk, E - e0);
  const int* key = dir ? esrc : edst;    // A: by dst, B: by src
  const int* oth = dir ? edst : esrc;
  for (int i = tid; i < len; i += 1024) {          // LDS sort
    unsigned ky = (unsigned)key[e0 + i], ot = (unsigned)oth[e0 + i];
    unsigned bbk = ky >> 4;
    unsigned slot = baseL[bbk] + atomicAdd(&cnt2[bbk], 1u);
    cmp[slot] = make_uint2((ot << 4) | (ky & 15u), __float_as_uint(wgt[e0 + i]));
    bktid[slot] = (unsigned char)bbk;
  }
  __syncthreads();
  for (int s = tid; s < len; s += 1024) {          // coalesced run copy-out
    unsigned bbk = bktid[s];
    out[myBase[bbk] + ((unsigned)s - baseL[bbk])] = cmp[s];
  }
}

// ---- K3/K4: per-bucket fine sort + select-free pipelined accumulation. --
// (Byte-identical to R19.) Records staged to LDS once; loads unconditional
// with clamped index; only the WEIGHT predicated.
__global__ void __launch_bounds__(1024) k_pass(
    const uint2* __restrict__ rec, const unsigned* __restrict__ seg,
    const float* __restrict__ vals, const float* __restrict__ x_t,
    const float* __restrict__ fx_t, float* __restrict__ eps_t,
    float* __restrict__ out, int N, int mode) {
  __shared__ uint2 stg[kTile];           // 20 KB staged records
  __shared__ uint2 srt[kTile];           // 20 KB node-sorted records
  __shared__ unsigned hW[16 * kNPB];     // per-wave private hist
  __shared__ unsigned wbase[16 * kNPB];  // absolute slot base per (wave,node)
  __shared__ unsigned wcur[16 * kNPB];
  __shared__ unsigned h[kNPB], hb[kNPB];
  __shared__ float red[1024];
  int tid = threadIdx.x, t = blockIdx.x;
  int segb = (int)seg[t], sege = (int)seg[t + 1];
  int wv = tid >> 6;
  int b = tid & 31, hw = tid >> 5, l = hw >> 1, part = hw & 1;
  float acc = 0.0f;

  for (int t0 = segb; t0 < sege; t0 += kTile) {    // 1 tile except 11-sigma tail
    int len = min(kTile, sege - t0);
    if (tid < 16 * kNPB) { hW[tid] = 0u; wcur[tid] = 0u; }
    __syncthreads();
    for (int i = tid; i < len; i += 1024) {        // stage + privatized hist
      uint2 r = rec[t0 + i];
      stg[i] = r;
      atomicAdd(&hW[wv * kNPB + (r.x & 15u)], 1u);
    }
    __syncthreads();
    if (tid < kNPB) {                              // cross-wave prefix per node
      unsigned run = 0;
#pragma unroll
      for (int w2 = 0; w2 < 16; ++w2) {
        unsigned c = hW[w2 * kNPB + tid];
        wbase[w2 * kNPB + tid] = run;
        run += c;
      }
      h[tid] = run;
    }
    __syncthreads();
    if (tid == 0) {                                // 16-elem excl scan
      unsigned run = 0;
#pragma unroll
      for (int l2 = 0; l2 < kNPB; ++l2) { hb[l2] = run; run += h[l2]; }
    }
    __syncthreads();
    if (tid < 16 * kNPB) wbase[tid] += hb[tid & (kNPB - 1)];
    __syncthreads();
    for (int i = tid; i < len; i += 1024) {        // fine sort (LDS -> LDS)
      uint2 r = stg[i];
      unsigned lx = r.x & 15u;
      srt[wbase[wv * kNPB + lx] + atomicAdd(&wcur[wv * kNPB + lx], 1u)] = r;
    }
    __syncthreads();

    int beg = (int)hb[l] + part, end = (int)hb[l] + (int)h[l];
    int last = end - 1; if (last < 0) last = 0;
    uint2 r0, r1, r2, r3, r4, r5, r6, r7;
    float v0, v1, v2, v3, v4, v5, v6, v7;
#define PC_LOAD(d)                                                   \
    { int p = beg + 2 * (d); uint2 rr = srt[min(p, last)];           \
      r##d = rr; v##d = vals[(((rr.x >> 4) & 4095u) << kLogB) + b]; }
    PC_LOAD(0) PC_LOAD(1) PC_LOAD(2) PC_LOAD(3)
    PC_LOAD(4) PC_LOAD(5) PC_LOAD(6) PC_LOAD(7)
#undef PC_LOAD
    int i = beg;
    while (i < end) {
#define PC_STEP(d)                                                   \
      { float wt = (i + 2 * (d) < end) ? __uint_as_float(r##d.y) : 0.0f; \
        acc = fmaf(wt, v##d, acc);                                   \
        int p = i + 16 + 2 * (d); uint2 rr = srt[min(p, last)];      \
        r##d = rr; v##d = vals[(((rr.x >> 4) & 4095u) << kLogB) + b]; }
      PC_STEP(0) PC_STEP(1) PC_STEP(2) PC_STEP(3)
      PC_STEP(4) PC_STEP(5) PC_STEP(6) PC_STEP(7)
#undef PC_STEP
      i += 16;
    }
    __syncthreads();                               // srt/hW reused next tile
  }

  red[tid] = acc;
  __syncthreads();
  if (part == 0) {                                 // combine 2 parts, write
    float s = red[tid] + red[tid + 32];
    int n = t * kNPB + l;
    int j = (n << kLogB) + b;
    if (mode == 0) {
      out[b * N + n] = s;                          // mu: full 64B line
      eps_t[j] = x_t[j] - s;
    } else {
      float fx = fx_t[j];
      out[b * N + n] = fmaf(1.0f - fx * fx, s, -eps_t[j]);  // dx
    }
  }
}

extern "C" void kernel_launch(void* const* d_in, const int* in_sizes, int n_in,
                              void* d_out, int out_size, void* d_ws, size_t ws_size,
                              hipStream_t stream) {
  const float* x    = (const float*)d_in[0];
  const float* w    = (const float*)d_in[1];
  const int*   esrc = (const int*)d_in[2];
  const int*   edst = (const int*)d_in[3];

  int BN = in_sizes[0];                  // 131072
  int E  = in_sizes[1];                  // 524288
  int N  = BN / kB;                      // 4096
  int nBB = (E + kChunk - 1) / kChunk;   // 128

  float* ws    = (float*)d_ws;
  float* x_t   = ws;                     // [BN]
  float* fx_t  = ws + (size_t)BN;        // [BN]
  float* eps_t = ws + 2 * (size_t)BN;    // [BN]
  unsigned* cntA = (unsigned*)(ws + 3 * (size_t)BN);    // [nBB*256] 128 KB
  unsigned* cntB = cntA + (size_t)nBB * kBkt;
  unsigned* segA = cntB + (size_t)nBB * kBkt;           // [257] (512 pad)
  unsigned* segB = segA + 512;
  uint2* recA = (uint2*)(segB + 512);                   // [E] 4 MB dense
  uint2* recB = recA + (size_t)E;                       // [E] 4 MB dense

  float* out_mu = (float*)d_out;
  float* out_dx = (float*)d_out + BN;

  k_hist<<<nBB + (N >> 6), 1024, 0, stream>>>(esrc, edst, x, x_t, fx_t,
                                              cntA, cntB, N, E, nBB);
  k_scatter<<<2 * nBB, 1024, 0, stream>>>(esrc, edst, w, cntA, cntB,
                                          recA, recB, segA, segB, E, nBB);
  // Pass 1: mu[n] = sum_{e: dst=n} w_e * fx[src_e]; eps = x - mu.
  k_pass<<<kBkt, 1024, 0, stream>>>(recA, segA, fx_t, x_t, fx_t,
                                    eps_t, out_mu, N, 0);
  // Pass 2: dx[n] = -eps[n] + f'(x_n) * sum_{e: src=n} w_e * eps[dst_e].
  k_pass<<<kBkt, 1024, 0, stream>>>(recB, segB, eps_t, x_t, fx_t,
                                    eps_t, out_dx, N, 1);
}

// Round 11
// 97.816 us; speedup vs baseline: 5.5956x; 1.0258x over previous
//
#include <hip/hip_runtime.h>

// Predictive-coding graph message passing, MI355X — round 21.
// R20 (100.3us, best). Calibrated budget: structural S~74-78us (256MiB
// workspace poison fill 41.5us + launch overhead — unattackable) + ~22us
// kernel work vs ~9-10us BW floor. Remaining kernels are ISSUE/LATENCY
// bound (hist: 4.5MB in 4us = 1.1TB/s, 6x under HBM ceiling; VALUBusy
// single-digit). R21 = R20 with edge reads vectorized (G13):
//   k_hist: 1x int4 esrc + 1x int4 edst per thread (kChunk/4 == 1024 ==
//           blockDim exactly) replaces 8 scalar iterations.
//   k_scatter: int4 key + int4 oth + float4 wgt per thread replaces 4
//           scalar iterations (12 VMEM issues -> 3).
// Scalar tail path kept for E % kChunk != 0. Everything else byte-identical
// to R20 (preamble, scans, copy-out, both k_pass bodies).

static constexpr int kB = 32, kLogB = 5;
static constexpr int kBkt = 256;        // coarse buckets (16 nodes each)
static constexpr int kNPB = 16;         // nodes per bucket
static constexpr int kChunk = 4096;     // edges per chunk block
static constexpr int kTile = 2560;      // pass LDS tile (mean 2048, +11sigma)

// ---- K1: per-chunk dual histograms + fused transpose/tanh. --------------
__global__ void __launch_bounds__(1024) k_hist(
    const int* __restrict__ esrc, const int* __restrict__ edst,
    const float* __restrict__ x, float* __restrict__ x_t,
    float* __restrict__ fx_t, unsigned* __restrict__ cntA,
    unsigned* __restrict__ cntB, int N, int E, int nBB) {
  __shared__ unsigned hA[kBkt], hB[kBkt];
  __shared__ float tile[32][65];
  int tid = threadIdx.x, blk = blockIdx.x;
  if (blk < nBB) {
    if (tid < kBkt) { hA[tid] = 0u; hB[tid] = 0u; }
    __syncthreads();
    int e0 = blk * kChunk;
    if (e0 + kChunk <= E) {              // full chunk: int4 fast path
      const int4* s4 = reinterpret_cast<const int4*>(esrc + e0);
      const int4* d4 = reinterpret_cast<const int4*>(edst + e0);
      int4 sv = s4[tid], dv = d4[tid];   // kChunk/4 == 1024 == blockDim
      atomicAdd(&hA[((unsigned)dv.x) >> 4], 1u);
      atomicAdd(&hA[((unsigned)dv.y) >> 4], 1u);
      atomicAdd(&hA[((unsigned)dv.z) >> 4], 1u);
      atomicAdd(&hA[((unsigned)dv.w) >> 4], 1u);
      atomicAdd(&hB[((unsigned)sv.x) >> 4], 1u);
      atomicAdd(&hB[((unsigned)sv.y) >> 4], 1u);
      atomicAdd(&hB[((unsigned)sv.z) >> 4], 1u);
      atomicAdd(&hB[((unsigned)sv.w) >> 4], 1u);
    } else {                             // tail chunk: scalar
      int len = E - e0;
      for (int i = tid; i < len; i += 1024) {
        atomicAdd(&hA[((unsigned)edst[e0 + i]) >> 4], 1u);
        atomicAdd(&hB[((unsigned)esrc[e0 + i]) >> 4], 1u);
      }
    }
    __syncthreads();
    if (tid < kBkt) {                    // non-atomic coalesced row write
      cntA[(size_t)blk * kBkt + tid] = hA[tid];
      cntB[(size_t)blk * kBkt + tid] = hB[tid];
    }
  } else if (blk - nBB < (N >> 6)) {
    int n0 = (blk - nBB) * 64;
    for (int k = tid; k < 32 * 64; k += 1024) {  // coalesced 256B rows
      int b = k >> 6, n = k & 63;
      tile[b][n] = x[b * N + n0 + n];
    }
    __syncthreads();
    for (int k = tid; k < 64 * 32; k += 1024) {  // coalesced t-layout
      int n = k >> 5, b = k & 31;
      float xv = tile[b][n];
      int j = (n0 + n) * kB + b;
      x_t[j] = xv;
      fx_t[j] = tanhf(xv);
    }
  }
}

// ---- K2: self-scanning deterministic scatter. 256 blocks (1/CU), one
// (direction, chunk) each. Preamble: coalesced read of the L2-resident
// [128][256] cnt matrix -> per-bucket {prefix-below-c, total} in one pass;
// single-wave shfl scan of totals gives global bucket bases. -----------
__global__ void __launch_bounds__(1024) k_scatter(
    const int* __restrict__ esrc, const int* __restrict__ edst,
    const float* __restrict__ wgt,
    const unsigned* __restrict__ cntA, const unsigned* __restrict__ cntB,
    uint2* __restrict__ recA, uint2* __restrict__ recB,
    unsigned* __restrict__ segA, unsigned* __restrict__ segB,
    int E, int nBB) {
  __shared__ unsigned qpre[4][kBkt], qtot[4][kBkt];
  __shared__ unsigned colPre[kBkt], colTot[kBkt], segL[kBkt];
  __shared__ unsigned myBase[kBkt], cntL[kBkt], baseL[kBkt], cnt2[kBkt];
  __shared__ uint2 cmp[kChunk];          // 32 KB chunk-sorted records
  __shared__ unsigned char bktid[kChunk];
  int tid = threadIdx.x, blk = blockIdx.x;
  int dir = (blk >= nBB);
  int c = blk - (dir ? nBB : 0);
  const unsigned* cnt = dir ? cntB : cntA;
  uint2* out = dir ? recB : recA;

  // Preamble: full-matrix column sums with prefix-below-c.
  int t = tid & (kBkt - 1), q = tid >> 8;
  int qlen = (nBB + 3) >> 2;
  int r0 = q * qlen;
  unsigned pre = 0, tot = 0;
  for (int j = 0; j < qlen; j += 8) {
    unsigned cc[8];
#pragma unroll
    for (int u = 0; u < 8; ++u) {        // 8 coalesced loads in flight
      int row = r0 + j + u;
      cc[u] = (row < nBB) ? cnt[(size_t)row * kBkt + t] : 0u;
    }
#pragma unroll
    for (int u = 0; u < 8; ++u) {
      int row = r0 + j + u;
      tot += cc[u];
      if (row < c) pre += cc[u];         // exact prefix contribution
    }
  }
  qpre[q][t] = pre;
  qtot[q][t] = tot;
  __syncthreads();
  if (tid < kBkt) {
    colPre[tid] = qpre[0][tid] + qpre[1][tid] + qpre[2][tid] + qpre[3][tid];
    colTot[tid] = qtot[0][tid] + qtot[1][tid] + qtot[2][tid] + qtot[3][tid];
  }
  __syncthreads();
  if (tid < 64) {                        // single-wave excl scan of totals
    int qq = tid << 2;
    unsigned c0 = colTot[qq], c1 = colTot[qq + 1];
    unsigned c2 = colTot[qq + 2], c3 = colTot[qq + 3];
    unsigned s = c0 + c1 + c2 + c3, run = s;
#pragma unroll
    for (int o = 1; o < 64; o <<= 1) {
      unsigned v = __shfl_up(run, o, 64);
      if (tid >= o) run += v;
    }
    unsigned bse = run - s;
    segL[qq] = bse; segL[qq + 1] = bse + c0;
    segL[qq + 2] = bse + c0 + c1; segL[qq + 3] = bse + c0 + c1 + c2;
  }
  __syncthreads();
  if (c == 0 && tid < kBkt) {            // publish segment bounds for k_pass
    unsigned* seg = dir ? segB : segA;
    seg[tid] = segL[tid];
    if (tid == kBkt - 1) seg[kBkt] = segL[tid] + colTot[tid];
  }
  if (tid < kBkt) {
    myBase[tid] = segL[tid] + colPre[tid];   // this chunk's global run base
    cntL[tid] = cnt[(size_t)c * kBkt + tid];
    cnt2[tid] = 0u;
  }
  __syncthreads();
  if (tid < 64) {                        // local excl scan of this chunk
    int qq = tid << 2;
    unsigned c0 = cntL[qq], c1 = cntL[qq + 1];
    unsigned c2 = cntL[qq + 2], c3 = cntL[qq + 3];
    unsigned s = c0 + c1 + c2 + c3, run = s;
#pragma unroll
    for (int o = 1; o < 64; o <<= 1) {
      unsigned v = __shfl_up(run, o, 64);
      if (tid >= o) run += v;
    }
    unsigned bse = run - s;
    baseL[qq] = bse; baseL[qq + 1] = bse + c0;
    baseL[qq + 2] = bse + c0 + c1; baseL[qq + 3] = bse + c0 + c1 + c2;
  }
  __syncthreads();
  int e0 = c * kChunk;
  const int* key = dir ? esrc : edst;    // A: by dst, B: by src
  const int* oth = dir ? edst : esrc;
#define SC_PUT(KY, OT, WT)                                           \
  { unsigned ky = (unsigned)(KY), ot = (unsigned)(OT);               \
    unsigned bbk = ky >> 4;                                          \
    unsigned slot = baseL[bbk] + atomicAdd(&cnt2[bbk], 1u);          \
    cmp[slot] = make_uint2((ot << 4) | (ky & 15u),                   \
                           __float_as_uint(WT));                     \
    bktid[slot] = (unsigned char)bbk; }
  int len;
  if (e0 + kChunk <= E) {                // full chunk: int4/float4 fast path
    len = kChunk;
    const int4* k4 = reinterpret_cast<const int4*>(key + e0);
    const int4* o4 = reinterpret_cast<const int4*>(oth + e0);
    const float4* w4 = reinterpret_cast<const float4*>(wgt + e0);
    int4 kv = k4[tid]; int4 ov = o4[tid]; float4 wv = w4[tid];
    SC_PUT(kv.x, ov.x, wv.x)
    SC_PUT(kv.y, ov.y, wv.y)
    SC_PUT(kv.z, ov.z, wv.z)
    SC_PUT(kv.w, ov.w, wv.w)
  } else {                               // tail chunk: scalar
    len = E - e0;
    for (int i = tid; i < len; i += 1024)
      SC_PUT(key[e0 + i], oth[e0 + i], wgt[e0 + i])
  }
#undef SC_PUT
  __syncthreads();
  for (int s = tid; s < len; s += 1024) {          // coalesced run copy-out
    unsigned bbk = bktid[s];
    out[myBase[bbk] + ((unsigned)s - baseL[bbk])] = cmp[s];
  }
}

// ---- K3/K4: per-bucket fine sort + select-free pipelined accumulation. --
// (Byte-identical to R20.) Records staged to LDS once; loads unconditional
// with clamped index; only the WEIGHT predicated.
__global__ void __launch_bounds__(1024) k_pass(
    const uint2* __restrict__ rec, const unsigned* __restrict__ seg,
    const float* __restrict__ vals, const float* __restrict__ x_t,
    const float* __restrict__ fx_t, float* __restrict__ eps_t,
    float* __restrict__ out, int N, int mode) {
  __shared__ uint2 stg[kTile];           // 20 KB staged records
  __shared__ uint2 srt[kTile];           // 20 KB node-sorted records
  __shared__ unsigned hW[16 * kNPB];     // per-wave private hist
  __shared__ unsigned wbase[16 * kNPB];  // absolute slot base per (wave,node)
  __shared__ unsigned wcur[16 * kNPB];
  __shared__ unsigned h[kNPB], hb[kNPB];
  __shared__ float red[1024];
  int tid = threadIdx.x, t = blockIdx.x;
  int segb = (int)seg[t], sege = (int)seg[t + 1];
  int wv = tid >> 6;
  int b = tid & 31, hw = tid >> 5, l = hw >> 1, part = hw & 1;
  float acc = 0.0f;

  for (int t0 = segb; t0 < sege; t0 += kTile) {    // 1 tile except 11-sigma tail
    int len = min(kTile, sege - t0);
    if (tid < 16 * kNPB) { hW[tid] = 0u; wcur[tid] = 0u; }
    __syncthreads();
    for (int i = tid; i < len; i += 1024) {        // stage + privatized hist
      uint2 r = rec[t0 + i];
      stg[i] = r;
      atomicAdd(&hW[wv * kNPB + (r.x & 15u)], 1u);
    }
    __syncthreads();
    if (tid < kNPB) {                              // cross-wave prefix per node
      unsigned run = 0;
#pragma unroll
      for (int w2 = 0; w2 < 16; ++w2) {
        unsigned c = hW[w2 * kNPB + tid];
        wbase[w2 * kNPB + tid] = run;
        run += c;
      }
      h[tid] = run;
    }
    __syncthreads();
    if (tid == 0) {                                // 16-elem excl scan
      unsigned run = 0;
#pragma unroll
      for (int l2 = 0; l2 < kNPB; ++l2) { hb[l2] = run; run += h[l2]; }
    }
    __syncthreads();
    if (tid < 16 * kNPB) wbase[tid] += hb[tid & (kNPB - 1)];
    __syncthreads();
    for (int i = tid; i < len; i += 1024) {        // fine sort (LDS -> LDS)
      uint2 r = stg[i];
      unsigned lx = r.x & 15u;
      srt[wbase[wv * kNPB + lx] + atomicAdd(&wcur[wv * kNPB + lx], 1u)] = r;
    }
    __syncthreads();

    int beg = (int)hb[l] + part, end = (int)hb[l] + (int)h[l];
    int last = end - 1; if (last < 0) last = 0;
    uint2 r0, r1, r2, r3, r4, r5, r6, r7;
    float v0, v1, v2, v3, v4, v5, v6, v7;
#define PC_LOAD(d)                                                   \
    { int p = beg + 2 * (d); uint2 rr = srt[min(p, last)];           \
      r##d = rr; v##d = vals[(((rr.x >> 4) & 4095u) << kLogB) + b]; }
    PC_LOAD(0) PC_LOAD(1) PC_LOAD(2) PC_LOAD(3)
    PC_LOAD(4) PC_LOAD(5) PC_LOAD(6) PC_LOAD(7)
#undef PC_LOAD
    int i = beg;
    while (i < end) {
#define PC_STEP(d)                                                   \
      { float wt = (i + 2 * (d) < end) ? __uint_as_float(r##d.y) : 0.0f; \
        acc = fmaf(wt, v##d, acc);                                   \
        int p = i + 16 + 2 * (d); uint2 rr = srt[min(p, last)];      \
        r##d = rr; v##d = vals[(((rr.x >> 4) & 4095u) << kLogB) + b]; }
      PC_STEP(0) PC_STEP(1) PC_STEP(2) PC_STEP(3)
      PC_STEP(4) PC_STEP(5) PC_STEP(6) PC_STEP(7)
#undef PC_STEP
      i += 16;
    }
    __syncthreads();                               // srt/hW reused next tile
  }

  red[tid] = acc;
  __syncthreads();
  if (part == 0) {                                 // combine 2 parts, write
    float s = red[tid] + red[tid + 32];
    int n = t * kNPB + l;
    int j = (n << kLogB) + b;
    if (mode == 0) {
      out[b * N + n] = s;                          // mu: full 64B line
      eps_t[j] = x_t[j] - s;
    } else {
      float fx = fx_t[j];
      out[b * N + n] = fmaf(1.0f - fx * fx, s, -eps_t[j]);  // dx
    }
  }
}

extern "C" void kernel_launch(void* const* d_in, const int* in_sizes, int n_in,
                              void* d_out, int out_size, void* d_ws, size_t ws_size,
                              hipStream_t stream) {
  const float* x    = (const float*)d_in[0];
  const float* w    = (const float*)d_in[1];
  const int*   esrc = (const int*)d_in[2];
  const int*   edst = (const int*)d_in[3];

  int BN = in_sizes[0];                  // 131072
  int E  = in_sizes[1];                  // 524288
  int N  = BN / kB;                      // 4096
  int nBB = (E + kChunk - 1) / kChunk;   // 128

  float* ws    = (float*)d_ws;
  float* x_t   = ws;                     // [BN]
  float* fx_t  = ws + (size_t)BN;        // [BN]
  float* eps_t = ws + 2 * (size_t)BN;    // [BN]
  unsigned* cntA = (unsigned*)(ws + 3 * (size_t)BN);    // [nBB*256] 128 KB
  unsigned* cntB = cntA + (size_t)nBB * kBkt;
  unsigned* segA = cntB + (size_t)nBB * kBkt;           // [257] (512 pad)
  unsigned* segB = segA + 512;
  uint2* recA = (uint2*)(segB + 512);                   // [E] 4 MB dense
  uint2* recB = recA + (size_t)E;                       // [E] 4 MB dense

  float* out_mu = (float*)d_out;
  float* out_dx = (float*)d_out + BN;

  k_hist<<<nBB + (N >> 6), 1024, 0, stream>>>(esrc, edst, x, x_t, fx_t,
                                              cntA, cntB, N, E, nBB);
  k_scatter<<<2 * nBB, 1024, 0, stream>>>(esrc, edst, w, cntA, cntB,
                                          recA, recB, segA, segB, E, nBB);
  // Pass 1: mu[n] = sum_{e: dst=n} w_e * fx[src_e]; eps = x - mu.
  k_pass<<<kBkt, 1024, 0, stream>>>(recA, segA, fx_t, x_t, fx_t,
                                    eps_t, out_mu, N, 0);
  // Pass 2: dx[n] = -eps[n] + f'(x_n) * sum_{e: src=n} w_e * eps[dst_e].
  k_pass<<<kBkt, 1024, 0, stream>>>(recB, segB, eps_t, x_t, fx_t,
                                    eps_t, out_dx, N, 1);
}